// Round 5
// baseline (574.223 us; speedup 1.0000x reference)
//
#include <hip/hip_runtime.h>
#include <math.h>
#include <stdint.h>

// Problem constants (fixed shapes per reference)
#define Bb   32
#define Tt   1024
#define Dd   512
#define Kk   64
#define K2   128     // 2K
#define Hh   4
#define KP   16
#define MLPD 2048
#define Mrows (Bb * Tt)   // 32768

// Conv window: mag <= sigmoid(-0.1)=0.475; 0.475^48 ~ 3e-16 -> exact to fp32
#define CW 48
#define CT 64

typedef unsigned short ushort_t;
typedef __attribute__((ext_vector_type(8))) short short8;     // 8 bf16 = 4 VGPRs
typedef __attribute__((ext_vector_type(4))) float floatx4;    // MFMA C/D

__device__ __forceinline__ float sigf(float x) { return 1.0f / (1.0f + __expf(-x)); }

__device__ __forceinline__ ushort_t f2bf(float f) {
    unsigned u = __float_as_uint(f);
    u += 0x7fffu + ((u >> 16) & 1u);   // round-to-nearest-even
    return (ushort_t)(u >> 16);
}
__device__ __forceinline__ float bf2f(ushort_t h) {
    return __uint_as_float(((unsigned)h) << 16);
}

// ---------------- LayerNorm: one wave per row of 512, bf16 output ----------------
__global__ __launch_bounds__(256) void ln_bf_kernel(const float* __restrict__ x,
                                                    const float* __restrict__ g,
                                                    const float* __restrict__ b,
                                                    ushort_t* __restrict__ o) {
    int row  = blockIdx.x * 4 + (threadIdx.x >> 6);
    int lane = threadIdx.x & 63;
    const float4* xr = (const float4*)(x + (size_t)row * Dd);
    float4 a = xr[lane];
    float4 c = xr[lane + 64];
    float s = a.x + a.y + a.z + a.w + c.x + c.y + c.z + c.w;
    float q = a.x * a.x + a.y * a.y + a.z * a.z + a.w * a.w
            + c.x * c.x + c.y * c.y + c.z * c.z + c.w * c.w;
#pragma unroll
    for (int m = 32; m > 0; m >>= 1) {
        s += __shfl_xor(s, m);
        q += __shfl_xor(q, m);
    }
    float mean = s * (1.0f / Dd);
    float var  = q * (1.0f / Dd) - mean * mean;
    float rs   = rsqrtf(var + 1e-5f);
    const float4* gg = (const float4*)g;
    const float4* bb = (const float4*)b;
    float4 g0 = gg[lane], g1 = gg[lane + 64];
    float4 b0 = bb[lane], b1 = bb[lane + 64];
    ushort4 r0, r1;
    r0.x = f2bf((a.x - mean) * rs * g0.x + b0.x);
    r0.y = f2bf((a.y - mean) * rs * g0.y + b0.y);
    r0.z = f2bf((a.z - mean) * rs * g0.z + b0.z);
    r0.w = f2bf((a.w - mean) * rs * g0.w + b0.w);
    r1.x = f2bf((c.x - mean) * rs * g1.x + b1.x);
    r1.y = f2bf((c.y - mean) * rs * g1.y + b1.y);
    r1.z = f2bf((c.z - mean) * rs * g1.z + b1.z);
    r1.w = f2bf((c.w - mean) * rs * g1.w + b1.w);
    ushort4* oo = (ushort4*)(o + (size_t)row * Dd);
    oo[lane]      = r0;
    oo[lane + 64] = r1;
}

// ---------------- fp32 [R,C] -> bf16 [C,R] transpose+convert ----------------
__global__ __launch_bounds__(256) void convert_transpose(const float* __restrict__ in,
                                                         ushort_t* __restrict__ out,
                                                         int R, int C) {
    __shared__ float t[32][33];
    int bx = blockIdx.x * 32;   // C offset
    int by = blockIdx.y * 32;   // R offset
    int tc = threadIdx.x & 31, tr = threadIdx.x >> 5;   // 8 rows per pass
#pragma unroll
    for (int i = 0; i < 4; i++)
        t[tr + 8 * i][tc] = in[(size_t)(by + tr + 8 * i) * C + bx + tc];
    __syncthreads();
#pragma unroll
    for (int i = 0; i < 4; i++)
        out[(size_t)(bx + tr + 8 * i) * R + by + tc] = f2bf(t[tc][tr + 8 * i]);
}

// ---------------- Kernel table precompute: kern[d][0..63]=real, [64..127]=imag ----
__global__ void kern_precompute(const float* __restrict__ log_decay,
                                const float* __restrict__ freq,
                                float* __restrict__ kern) {
    int i = blockIdx.x * 256 + threadIdx.x;
    if (i >= CW * Kk) return;
    int d = i >> 6, k = i & 63;
    float mag = 1.0f / (1.0f + expf(-log_decay[k]));
    float mp  = powf(mag, (float)d);
    float ph  = (float)d * freq[k];
    kern[d * K2 + k]      = mp * cosf(ph);
    kern[d * K2 + 64 + k] = mp * sinf(ph);
}

// ---------------- Windowed causal complex conv + per-head coupling ----------------
__global__ __launch_bounds__(256) void conv_kernel(const float* __restrict__ beta,
                                                   const float* __restrict__ kern,
                                                   const float* __restrict__ coup,
                                                   float* __restrict__ eig,
                                                   ushort_t* __restrict__ eigb) {
    __shared__ float sBeta[CT + CW][K2];   // 56 KB
    __shared__ float sCoup[Hh][KP][KP];    // transposed: [h][k][j]
    int b   = blockIdx.y;
    int t0  = blockIdx.x * CT;
    int tid = threadIdx.x;
    for (int i = tid; i < Hh * KP * KP; i += 256) {
        int h = i >> 8, j = (i >> 4) & 15, kk = i & 15;
        sCoup[h][kk][j] = coup[i];
    }
    for (int i = tid; i < (CT + CW) * K2; i += 256) {
        int r = i >> 7, c = i & 127;
        int t = t0 - CW + r;
        sBeta[r][c] = (t >= 0) ? beta[((size_t)b * Tt + t) * K2 + c] : 0.0f;
    }
    __syncthreads();
    int k  = tid & 63;
    int ts = tid >> 6;
    float cr[16], ci[16];
#pragma unroll
    for (int i = 0; i < 16; i++) { cr[i] = 0.0f; ci[i] = 0.0f; }
    for (int d = 0; d < CW; d++) {
        float kr = kern[d * K2 + k];
        float ki = kern[d * K2 + 64 + k];
#pragma unroll
        for (int i = 0; i < 16; i++) {
            int r    = CW + ts + 4 * i - d;
            float br = sBeta[r][k];
            float bi = sBeta[r][64 + k];
            cr[i] += kr * br - ki * bi;
            ci[i] += kr * bi + ki * br;
        }
    }
    __syncthreads();
#pragma unroll
    for (int i = 0; i < 16; i++) {
        int tl = ts + 4 * i;
        sBeta[tl][k]      = cr[i];
        sBeta[tl][64 + k] = ci[i];
    }
    __syncthreads();
    int h = k >> 4, jj = k & 15;
#pragma unroll
    for (int i = 0; i < 16; i++) {
        int tl = ts + 4 * i;
        float er = 0.0f, ei = 0.0f;
#pragma unroll
        for (int kk = 0; kk < KP; kk++) {
            float w = sCoup[h][kk][jj];
            er += w * sBeta[tl][h * KP + kk];
            ei += w * sBeta[tl][64 + h * KP + kk];
        }
        size_t off = ((size_t)b * Tt + t0 + tl) * K2;
        eig[off + k]       = er;
        eig[off + 64 + k]  = ei;
        eigb[off + k]      = f2bf(er);
        eigb[off + 64 + k] = f2bf(ei);
    }
}

// ---------------- bf16 MFMA GEMM, register-staged pipeline ----------------
// 128x128 tile, BK=32, 256 threads (4 waves, each 64x64 = 4x4 of 16x16x32 MFMA).
// Staging path: global_load_dwordx4 -> VGPR -> ds_write_b128 (AITER-style).
// Register loads are thread-private, so the compiler does NOT drain them at
// s_barrier (unlike global_load_lds, which forces vmcnt(0) at every barrier).
// vmcnt(N) is inserted only before the ds_write one iteration later -> loads
// stay in flight across the barrier and latency is covered by a full K-step.
// 2 LDS stages x 16 KB; one barrier per step (write stage p -> barrier ->
// read stage p; next step writes the other stage: WAR-safe, see hazard note).
// Grid is 1-D XCD-swizzled (N-blocks of one A-strip share lin%8 -> same XCD L2).
// LDS colgroup swizzle p=(g+(row>>1))&3 applied on the global source address.
enum { EPI_INCOMB = 0, EPI_X1, EPI_SILU, EPI_OUT0, EPI_OUTA };

#define STG 16384

template <int EPI>
__global__ __launch_bounds__(256) void mfma_gemm(
    const ushort_t* __restrict__ A, const ushort_t* __restrict__ Bt,
    void* __restrict__ Cv, void* __restrict__ Cv2, int K, int ldb, int ldc,
    int gx,
    const float* __restrict__ bias,
    const float* __restrict__ aux1, const ushort_t* __restrict__ aux2) {
    __shared__ __align__(16) char lds[2 * STG];
    int tid  = threadIdx.x;
    int lane = tid & 63, w = tid >> 6;
    // XCD-aware decode (M-block count must be divisible by 8; 256 is)
    int lin  = blockIdx.x;
    int xcd  = lin & 7;
    int rest = lin >> 3;
    int bx   = rest % gx;
    int by   = xcd + 8 * (rest / gx);
    int bm = by * 128, bn = bx * 128;
    int wm = (w >> 1) * 64, wn = (w & 1) * 64;

    // staging: each wave covers 2 A-chunks + 2 B-chunks of 1 KB (64 lanes x 16 B)
    const char* gA[2];
    const char* gB[2];
    int lofsA[2], lofsB[2];
#pragma unroll
    for (int q = 0; q < 2; q++) {
        int c = 2 * w + q;
        int m = c * 16 + (lane >> 2);                 // tile row this lane feeds
        int g = ((lane & 3) - ((m >> 1) & 3)) & 3;    // logical k-colgroup (swizzle)
        gA[q] = (const char*)(A  + (size_t)(bm + m) * K   + g * 8);
        gB[q] = (const char*)(Bt + (size_t)(bn + m) * ldb + g * 8);
        lofsA[q] = c * 1024 + lane * 16;
        lofsB[q] = 8192 + c * 1024 + lane * 16;
    }
    // fragment LDS byte offsets (swizzle-aware), fixed across K loop
    int aoff[4], boff[4];
#pragma unroll
    for (int i = 0; i < 4; i++) {
        int m = wm + i * 16 + (lane & 15);
        aoff[i] = m * 64 + ((((lane >> 4) + (m >> 1)) & 3) * 16);
        int n = wn + i * 16 + (lane & 15);
        boff[i] = 8192 + n * 64 + ((((lane >> 4) + (n >> 1)) & 3) * 16);
    }
    floatx4 acc[4][4];
#pragma unroll
    for (int i = 0; i < 4; i++)
#pragma unroll
        for (int j = 0; j < 4; j++) acc[i][j] = (floatx4)0.0f;

    // preload step-0 global data into registers
    float4 rA0 = *(const float4*)gA[0];
    float4 rA1 = *(const float4*)gA[1];
    float4 rB0 = *(const float4*)gB[0];
    float4 rB1 = *(const float4*)gB[1];

    int ns = K >> 5;
    for (int k = 0; k < ns; k++) {
        char* st = lds + (size_t)(k & 1) * STG;
        // ds_write stage (k&1): compiler inserts vmcnt wait for the loads
        // issued one iteration ago (full step of latency cover).
        *(float4*)(st + lofsA[0]) = rA0;
        *(float4*)(st + lofsA[1]) = rA1;
        *(float4*)(st + lofsB[0]) = rB0;
        *(float4*)(st + lofsB[1]) = rB1;
        if (k + 1 < ns) {   // issue loads for step k+1; stay in flight across barrier
            size_t kb = (size_t)(k + 1) * 64;
            rA0 = *(const float4*)(gA[0] + kb);
            rA1 = *(const float4*)(gA[1] + kb);
            rB0 = *(const float4*)(gB[0] + kb);
            rB1 = *(const float4*)(gB[1] + kb);
        }
        __syncthreads();   // drains lgkmcnt (ds_writes) only; vm loads stay in flight
        const char* s = st;
        short8 af[4], bfr[4];
#pragma unroll
        for (int i = 0; i < 4; i++) af[i]  = *(const short8*)(s + aoff[i]);
#pragma unroll
        for (int j = 0; j < 4; j++) bfr[j] = *(const short8*)(s + boff[j]);
#pragma unroll
        for (int i = 0; i < 4; i++)
#pragma unroll
            for (int j = 0; j < 4; j++)
                acc[i][j] = __builtin_amdgcn_mfma_f32_16x16x32_bf16(af[i], bfr[j], acc[i][j], 0, 0, 0);
        // no trailing barrier needed: next iter writes the OTHER stage; a wave
        // can only be 2 iters ahead by passing the next barrier, which requires
        // all waves to have finished this iter's ds_reads (lgkm-drained pre-MFMA).
    }
    // epilogue: C/D layout col=lane&15, row=(lane>>4)*4+reg
    int rq = (lane >> 4) * 4;
    int cn = lane & 15;
#pragma unroll
    for (int i = 0; i < 4; i++) {
#pragma unroll
        for (int j = 0; j < 4; j++) {
            int col = bn + wn + j * 16 + cn;
#pragma unroll
            for (int r = 0; r < 4; r++) {
                int row    = bm + wm + i * 16 + rq + r;
                float v    = acc[i][j][r];
                if (EPI == EPI_INCOMB) {
                    // cols 0..127 -> beta fp32 [M,128]; cols 128..639 -> gate bf16 [M,512]
                    if (bx == 0) {
                        ((float*)Cv)[(size_t)row * K2 + col] = v;
                    } else {
                        int gc = col - 128;
                        ((ushort_t*)Cv2)[(size_t)row * Dd + gc] = f2bf(sigf(v + bias[gc]));
                    }
                } else if (EPI == EPI_X1) {
                    size_t off = (size_t)row * ldc + col;
                    ((float*)Cv)[off] = aux1[off] + bf2f(aux2[off]) * v;
                } else if (EPI == EPI_SILU) {
                    size_t off = (size_t)row * ldc + col;
                    float t = v + bias[col];
                    ((ushort_t*)Cv)[off] = f2bf(t * sigf(t));
                } else if (EPI == EPI_OUT0) {
                    size_t off = (size_t)row * ldc + col;
                    float* C = (float*)Cv;
                    C[off] = C[off] + v + bias[col];   // C holds x1; adds b2
                } else {  // EPI_OUTA
                    size_t off = (size_t)row * ldc + col;
                    ((float*)Cv)[off] += v;
                }
            }
        }
    }
}

extern "C" void kernel_launch(void* const* d_in, const int* in_sizes, int n_in,
                              void* d_out, int out_size, void* d_ws, size_t ws_size,
                              hipStream_t stream) {
    (void)in_sizes; (void)n_in; (void)out_size;
    const float* x         = (const float*)d_in[0];
    const float* w_in      = (const float*)d_in[1];
    const float* log_decay = (const float*)d_in[2];
    const float* frequency = (const float*)d_in[3];
    const float* coupling  = (const float*)d_in[4];
    const float* w_out     = (const float*)d_in[5];
    const float* w_gate    = (const float*)d_in[6];
    const float* b_gate    = (const float*)d_in[7];
    const float* w1        = (const float*)d_in[8];
    const float* b1        = (const float*)d_in[9];
    const float* w2        = (const float*)d_in[10];
    const float* b2        = (const float*)d_in[11];
    const float* g1        = (const float*)d_in[12];
    const float* bn1       = (const float*)d_in[13];
    const float* g2        = (const float*)d_in[14];
    const float* bn2       = (const float*)d_in[15];

    float* out = (float*)d_out;                        // [32768,512]; holds x1 then final
    float* eig = (float*)d_out + (size_t)Mrows * Dd;   // [32768,128] fp32 output

    // ws layout (MB offsets)
    char* ws = (char*)d_ws;
    ushort_t* xn      = (ushort_t*)(ws);                     // 32 MB  [M,512] bf16
    ushort_t* xn2     = (ushort_t*)(ws + (32ull  << 20));    // 32 MB
    float*    beta    = (float*)   (ws + (64ull  << 20));    // 16 MB  [M,128] fp32
    ushort_t* eigb    = (ushort_t*)(ws + (80ull  << 20));    //  8 MB  [M,128] bf16
    ushort_t* gateb   = (ushort_t*)(ws + (88ull  << 20));    // 32 MB  [M,512] bf16
    ushort_t* w_comb  = (ushort_t*)(ws + (120ull << 20));    // [640,512] bf16 = 640 KB
    ushort_t* w_outT  = (ushort_t*)(ws + (122ull << 20));    // [512,128]
    ushort_t* w1T     = (ushort_t*)(ws + (123ull << 20));    // [2048,512] (2 MB)
    ushort_t* w2T     = (ushort_t*)(ws + (125ull << 20));    // [512,2048] (2 MB)
    float*    kern    = (float*)   (ws + (127ull << 20));    // 24 KB

    // MLP hidden chunk: prefer tail of ws; else reuse dead xn region (32 MB)
    size_t base = 128ull << 20;
    ushort_t* hid;
    int CC;
    if (ws_size >= base + ((size_t)Mrows * 2048 * 2)) { hid = (ushort_t*)(ws + base); CC = 2048; }
    else if (ws_size >= base + ((size_t)Mrows * 1024 * 2)) { hid = (ushort_t*)(ws + base); CC = 1024; }
    else { hid = (ushort_t*)ws; CC = 512; }   // xn is dead by MLP time
    int nch = MLPD / CC;

    dim3 blk(256);
    // weight transpose+convert. w_in and w_gate land adjacently in w_comb [640,512].
    convert_transpose<<<dim3(K2 / 32, Dd / 32), blk, 0, stream>>>(w_in, w_comb, Dd, K2);
    convert_transpose<<<dim3(Dd / 32, Dd / 32), blk, 0, stream>>>(w_gate, w_comb + (size_t)K2 * Dd, Dd, Dd);
    convert_transpose<<<dim3(Dd / 32, K2 / 32), blk, 0, stream>>>(w_out, w_outT, K2, Dd);
    convert_transpose<<<dim3(MLPD / 32, Dd / 32), blk, 0, stream>>>(w1, w1T, Dd, MLPD);
    convert_transpose<<<dim3(Dd / 32, MLPD / 32), blk, 0, stream>>>(w2, w2T, MLPD, Dd);
    kern_precompute<<<dim3((CW * Kk + 255) / 256), blk, 0, stream>>>(log_decay, frequency, kern);

    // xn = LN(x) -> bf16
    ln_bf_kernel<<<dim3(Mrows / 4), blk, 0, stream>>>(x, g1, bn1, xn);
    // fused: [beta | gate] = xn @ [w_in | w_gate]  (N=640), XCD-swizzled 1-D grid
    mfma_gemm<EPI_INCOMB><<<dim3(5 * 256), blk, 0, stream>>>(
        xn, w_comb, beta, gateb, Dd, Dd, 0, 5, b_gate, nullptr, nullptr);
    // eigenstates: windowed conv + coupling -> eig (fp32 out) + eigb (bf16)
    conv_kernel<<<dim3(Tt / CT, Bb), blk, 0, stream>>>(beta, kern, coupling, eig, eigb);
    // x1 = x + gate * (eig @ w_out)  -> d_out[0:64MB]
    mfma_gemm<EPI_X1><<<dim3(4 * 256), blk, 0, stream>>>(
        eigb, w_outT, out, nullptr, K2, K2, Dd, 4, nullptr, x, gateb);
    // xn2 = LN(x1) -> bf16
    ln_bf_kernel<<<dim3(Mrows / 4), blk, 0, stream>>>(out, g2, bn2, xn2);
    // MLP: out = x1 + b2 + sum_c silu(xn2@w1_c + b1_c)@w2_c
    for (int c = 0; c < nch; c++) {
        mfma_gemm<EPI_SILU><<<dim3((CC / 128) * 256), blk, 0, stream>>>(
            xn2, w1T + (size_t)c * CC * Dd, hid, nullptr, Dd, Dd, CC, CC / 128, b1 + (size_t)c * CC, nullptr, nullptr);
        if (c == 0) {
            mfma_gemm<EPI_OUT0><<<dim3(4 * 256), blk, 0, stream>>>(
                hid, w2T + (size_t)c * CC, out, nullptr, CC, MLPD, Dd, 4, b2, nullptr, nullptr);
        } else {
            mfma_gemm<EPI_OUTA><<<dim3(4 * 256), blk, 0, stream>>>(
                hid, w2T + (size_t)c * CC, out, nullptr, CC, MLPD, Dd, 4, nullptr, nullptr, nullptr);
        }
    }
}